// Round 9
// baseline (298.999 us; speedup 1.0000x reference)
//
#include <hip/hip_runtime.h>
#include <cstdint>
#include <cstddef>

#define NUM_USERS 100000
#define NUM_ITEMS 100000
#define NUM_NODES 200000
#define NUM_EDGES 4000000
#define BATCH     4096
#define EMB       64

#define NB    391          // ceil(NUM_NODES / 512) buckets (bucket = row >> 9)
#define CAP   11264        // fixed bucket capacity: mean 10240 + 10 sigma; = 11*1024
#define CHUNK 8192         // edges per block in k_part1 (489 blocks)
#define PTHREADS 1024
#define EPB   8            // CHUNK / PTHREADS
#define RPT   11           // CAP / 1024: tmp records per thread in k_part2
#define BCAP  64           // per-batch-node edge-list capacity (deg~Poisson(20))
#define NWORDS 6250        // ceil(NUM_NODES / 32) bitmap words

// ---------------- bf16 helpers (round-to-nearest-even) ----------------

__device__ __forceinline__ unsigned short f2bf(float f) {
    unsigned u = __float_as_uint(f);
    u = (u + 0x7FFFu + ((u >> 16) & 1u)) >> 16;
    return (unsigned short)u;
}
__device__ __forceinline__ float bf2f(unsigned short b) {
    return __uint_as_float(((unsigned)b) << 16);
}

// ---------------- Pass 1: cvt + batch-marking + LDS-sorted partition ----------
// r7-passed form with two micro-fixes:
//  (a) hist-zero barrier moved BEFORE the cvt loop so cvt's VMEM stream
//      overlaps the count phase's LDS atomics (no fence between them);
//  (b) copy-out uses 16-lane groups (4 buckets/wave): avg bucket run is
//      ~21 recs, so 64-lane-per-bucket wasted 2/3 of lanes and ran ~33
//      serial iterations/wave; groups cut that to ~8 at 21/32 utilization.
// Record pack: x = (row&511)<<18 | col  (9+18 bits), y = f32 val bits.

__global__ void k_part1(const int* __restrict__ user, const int* __restrict__ pos,
                        const int* __restrict__ neg,
                        const int* __restrict__ erow, const int* __restrict__ ecol,
                        const float* __restrict__ eval_,
                        const float* __restrict__ uemb, const float* __restrict__ iemb,
                        unsigned short* __restrict__ xb,
                        int* __restrict__ bcur,
                        unsigned* __restrict__ memb, unsigned* __restrict__ need,
                        int* __restrict__ midx,
                        int2* __restrict__ tmp) {
    __shared__ int  hist[NB];
    __shared__ int  sst[512];          // inclusive scan of hist (padded)
    __shared__ int  gb[NB];            // global base per bucket
    __shared__ int  wpre[8];           // per-wave partial sums for shfl scan
    __shared__ int2 srec[CHUNK];       // 64 KB block-sorted records
    int t = threadIdx.x;
    int gid = blockIdx.x * PTHREADS + t;
    if (t < NB) hist[t] = 0;
    __syncthreads();                   // hist visible; cvt/mark/count share one region

    // fused cvt: f32 emb -> bf16 xb (3.2 grid-stride iters over 489x1024 threads)
    const int TOT8 = (NUM_NODES * EMB) / 8;              // 1.6M chunks of 8
    const size_t UELEMS = (size_t)NUM_USERS * EMB;       // divisible by 8
    for (int i = gid; i < TOT8; i += gridDim.x * PTHREADS) {
        size_t off = (size_t)i * 8;
        const float* src = (off < UELEMS) ? (uemb + off) : (iemb + (off - UELEMS));
        float4 f0 = ((const float4*)src)[0];
        float4 f1 = ((const float4*)src)[1];
        ((ushort4*)(xb + off))[0] = make_ushort4(f2bf(f0.x), f2bf(f0.y), f2bf(f0.z), f2bf(f0.w));
        ((ushort4*)(xb + off))[1] = make_ushort4(f2bf(f1.x), f2bf(f1.y), f2bf(f1.z), f2bf(f1.w));
    }
    // fused batch-node marking (consumers: k_part2, k_spmm1, k_final — later kernels)
    if (gid < 3 * BATCH) {
        int b = gid & (BATCH - 1);
        int w = gid >> 12;
        int node = (w == 0) ? user[b] : (w == 1) ? (NUM_USERS + pos[b]) : (NUM_USERS + neg[b]);
        unsigned bit = 1u << (node & 31);
        atomicOr(&memb[node >> 5], bit);
        atomicOr(&need[node >> 5], bit);   // batch nodes' own h1 rows read by k_final
        midx[node] = gid;                  // duplicate nodes: any single winner is fine
    }

    // count phase (independent of cvt/mark; no barrier between — they overlap)
    int start = blockIdx.x * CHUNK;
    int rows[EPB], ranks[EPB];
#pragma unroll
    for (int k = 0; k < EPB; ++k) {
        int e = start + t + k * PTHREADS;
        if (e < NUM_EDGES) {
            int r = erow[e];
            rows[k]  = r;
            ranks[k] = atomicAdd(&hist[r >> 9], 1);
        } else {
            rows[k] = -1;
        }
    }
    __syncthreads();

    // two-level shfl scan of hist -> inclusive sst[0..511] (3 barriers total)
    int lane = t & 63, wv8 = t >> 6;
    int v = (t < 512) ? ((t < NB) ? hist[t] : 0) : 0;
    int inc = v;
#pragma unroll
    for (int off = 1; off < 64; off <<= 1) {
        int nv = __shfl_up(inc, off, 64);
        if (lane >= off) inc += nv;
    }
    if (t < 512 && lane == 63) wpre[wv8] = inc;
    __syncthreads();
    if (t < 64) {
        int sv = (t < 8) ? wpre[t] : 0;
#pragma unroll
        for (int off = 1; off < 8; off <<= 1) {
            int nv = __shfl_up(sv, off, 64);
            if (t >= off) sv += nv;
        }
        if (t < 8) wpre[t] = sv;
    }
    __syncthreads();
    if (t < 512) sst[t] = inc + (wv8 ? wpre[wv8 - 1] : 0);
    // global cursor reservation (relative bcur)
    if (t < NB) gb[t] = atomicAdd(&bcur[t], hist[t]);
    __syncthreads();

    // LDS scatter into block-sorted order (NO side channel — r2 form)
#pragma unroll
    for (int k = 0; k < EPB; ++k) {
        if (rows[k] >= 0) {
            int e   = start + t + k * PTHREADS;
            int r   = rows[k];
            int bkt = r >> 9;
            int lp  = sst[bkt] - hist[bkt] + ranks[k];   // excl start + rank
            srec[lp] = make_int2(((r & 511) << 18) | ecol[e], __float_as_int(eval_[e]));
        }
    }
    __syncthreads();

    // coalesced copy-out: 16-lane group per bucket run (4 buckets per wave)
    int grp = t >> 4, gl = t & 15;                       // 64 groups
    for (int bkt = grp; bkt < NB; bkt += 64) {
        int c  = hist[bkt];
        int st = sst[bkt] - c;
        int g0 = gb[bkt];
        size_t base = (size_t)bkt * CAP;
        for (int j = gl; j < c; j += 16) {
            int rel = g0 + j;
            if (rel < CAP)   // overflow clamp (P ~ 1e-12, deterministic input)
                tmp[base + rel] = srec[st + j];
        }
    }
}

// ---------------- Pass 2: per-bucket row-sort IN-PLACE + batch side-channel ----
// (byte-identical to r7-passed version)

__global__ void k_part2(const int* __restrict__ bcur, int2* tmp,
                        int2* __restrict__ rowext,
                        const unsigned* __restrict__ memb, const int* __restrict__ midx,
                        unsigned* __restrict__ need,
                        int* __restrict__ bcnt, int2* __restrict__ bedge) {
    __shared__ int cnt[512];
    __shared__ int loc[512];
    __shared__ int wpre[8];
    __shared__ unsigned mw[16];
    int b = blockIdx.x, t = threadIdx.x;
    int base_row = b << 9;
    int nrows = min(512, NUM_NODES - base_row);
    int s0 = b * CAP;
    int n = min(bcur[b], CAP);
    if (t < 512) cnt[t] = 0;
    if (t < 16) mw[t] = memb[(base_row >> 5) + t];   // memb padded to 6256 words
    __syncthreads();

    int2 r[RPT];
#pragma unroll
    for (int i = 0; i < RPT; ++i) {
        int idx = t + i * 1024;
        if (idx < n) {
            r[i] = tmp[s0 + idx];
            atomicAdd(&cnt[((unsigned)r[i].x) >> 18], 1);
        }
    }
    __syncthreads();

    // two-level shfl scan of cnt -> inclusive (3 barriers)
    int lane = t & 63, wv8 = t >> 6;
    int v = (t < 512) ? cnt[t] : 0;
    int inc = v;
#pragma unroll
    for (int off = 1; off < 64; off <<= 1) {
        int nv = __shfl_up(inc, off, 64);
        if (lane >= off) inc += nv;
    }
    if (t < 512 && lane == 63) wpre[wv8] = inc;
    __syncthreads();
    if (t < 64) {
        int sv = (t < 8) ? wpre[t] : 0;
#pragma unroll
        for (int off = 1; off < 8; off <<= 1) {
            int nv = __shfl_up(sv, off, 64);
            if (t >= off) sv += nv;
        }
        if (t < 8) wpre[t] = sv;
    }
    __syncthreads();
    if (t < 512) {
        int incl = inc + (wv8 ? wpre[wv8 - 1] : 0);
        int cur = s0 + incl - v;    // exclusive, bucket-local
        if (t < nrows) rowext[base_row + t] = make_int2(cur, v);
        loc[t] = cur;
    }
    __syncthreads();

#pragma unroll
    for (int i = 0; i < RPT; ++i) {
        int idx = t + i * 1024;
        if (idx < n) {
            int2 rec = r[i];
            unsigned rl = ((unsigned)rec.x) >> 18;
            int p = atomicAdd(&loc[rl], 1);
            int col = rec.x & 0x3FFFF;
            tmp[p] = make_int2(col, rec.y);          // in-place, row bits stripped
            if ((mw[rl >> 5] >> (rl & 31)) & 1u) {   // batch-node row (~6%)
                int cs = midx[base_row + (int)rl];
                int bp = atomicAdd(&bcnt[cs], 1);
                if (bp < BCAP) bedge[cs * BCAP + bp] = make_int2(col, rec.y);
                atomicOr(&need[col >> 5], 1u << (col & 31));
            }
        }
    }
}

// ---------------- SpMM layer 1: h1 = A * x, NEEDED ROWS ONLY ----------------
// (byte-identical to r7-passed version: 16-edge unpredicated main loop)

__global__ void k_spmm1(const int2* __restrict__ rowext, const int2* __restrict__ epack,
                        const unsigned short* __restrict__ xb,
                        const unsigned* __restrict__ need,
                        unsigned short* __restrict__ h1) {
    int wid  = (blockIdx.x * blockDim.x + threadIdx.x) >> 6;
    int lane = threadIdx.x & 63;
    if (wid >= NUM_NODES) return;
    if (!((need[wid >> 5] >> (wid & 31)) & 1u)) return;
    int g = lane >> 4;
    int q = (lane & 15) * 4;
    int2 se = rowext[wid];
    int s = se.x, t = se.x + se.y;
    float a0 = 0.f, a1 = 0.f, a2 = 0.f, a3 = 0.f;
    int e = s;
    int tfull = s + ((t - s) & ~15);
    for (; e < tfull; e += 16) {       // unpredicated hot loop, 16 edges
        int2 p0 = epack[e + g];
        int2 p1 = epack[e + 4 + g];
        int2 p2 = epack[e + 8 + g];
        int2 p3 = epack[e + 12 + g];
        ushort4 x0 = *(const ushort4*)(xb + (size_t)p0.x * EMB + q);
        ushort4 x1 = *(const ushort4*)(xb + (size_t)p1.x * EMB + q);
        ushort4 x2 = *(const ushort4*)(xb + (size_t)p2.x * EMB + q);
        ushort4 x3 = *(const ushort4*)(xb + (size_t)p3.x * EMB + q);
        float v0 = __int_as_float(p0.y);
        float v1 = __int_as_float(p1.y);
        float v2 = __int_as_float(p2.y);
        float v3 = __int_as_float(p3.y);
        a0 = fmaf(v0, bf2f(x0.x), a0); a1 = fmaf(v0, bf2f(x0.y), a1);
        a2 = fmaf(v0, bf2f(x0.z), a2); a3 = fmaf(v0, bf2f(x0.w), a3);
        a0 = fmaf(v1, bf2f(x1.x), a0); a1 = fmaf(v1, bf2f(x1.y), a1);
        a2 = fmaf(v1, bf2f(x1.z), a2); a3 = fmaf(v1, bf2f(x1.w), a3);
        a0 = fmaf(v2, bf2f(x2.x), a0); a1 = fmaf(v2, bf2f(x2.y), a1);
        a2 = fmaf(v2, bf2f(x2.z), a2); a3 = fmaf(v2, bf2f(x2.w), a3);
        a0 = fmaf(v3, bf2f(x3.x), a0); a1 = fmaf(v3, bf2f(x3.y), a1);
        a2 = fmaf(v3, bf2f(x3.z), a2); a3 = fmaf(v3, bf2f(x3.w), a3);
    }
    for (; e < t; e += 8) {            // predicated tail (<=2 iterations)
        int eA = e + g, eB = e + 4 + g;
        int2 pA = epack[eA < t ? eA : s];
        int2 pB = epack[eB < t ? eB : s];
        float vA = (eA < t) ? __int_as_float(pA.y) : 0.f;
        float vB = (eB < t) ? __int_as_float(pB.y) : 0.f;
        ushort4 xA = *(const ushort4*)(xb + (size_t)pA.x * EMB + q);
        ushort4 xB = *(const ushort4*)(xb + (size_t)pB.x * EMB + q);
        a0 = fmaf(vA, bf2f(xA.x), a0); a1 = fmaf(vA, bf2f(xA.y), a1);
        a2 = fmaf(vA, bf2f(xA.z), a2); a3 = fmaf(vA, bf2f(xA.w), a3);
        a0 = fmaf(vB, bf2f(xB.x), a0); a1 = fmaf(vB, bf2f(xB.y), a1);
        a2 = fmaf(vB, bf2f(xB.z), a2); a3 = fmaf(vB, bf2f(xB.w), a3);
    }
    a0 += __shfl_xor(a0, 16, 64); a1 += __shfl_xor(a1, 16, 64);
    a2 += __shfl_xor(a2, 16, 64); a3 += __shfl_xor(a3, 16, 64);
    a0 += __shfl_xor(a0, 32, 64); a1 += __shfl_xor(a1, 32, 64);
    a2 += __shfl_xor(a2, 32, 64); a3 += __shfl_xor(a3, 32, 64);
    if (lane < 16) {
        ushort4 o = make_ushort4(f2bf(a0), f2bf(a1), f2bf(a2), f2bf(a3));
        *(ushort4*)(h1 + (size_t)wid * EMB + q) = o;
    }
}

// ---------------- Fused layer 2 + scoring: 4 batch items per block ----------
// Was 4096 blocks x 192 threads (3 waves) — dispatch-overhead-dominated for
// ~20-edge gathers. Now 1024 blocks x 768 threads (12 waves = 4 items x 3
// roles); score math preserved: prod = user-slice * {pos,neg}-slice.

__device__ __forceinline__ const float* node_ptr(int c, const float* __restrict__ uemb,
                                                 const float* __restrict__ iemb) {
    return (c < NUM_USERS) ? (uemb + (size_t)c * EMB)
                           : (iemb + (size_t)(c - NUM_USERS) * EMB);
}

__global__ void k_final(const int* __restrict__ user, const int* __restrict__ pos,
                        const int* __restrict__ neg,
                        const int* __restrict__ midx, const int* __restrict__ bcnt,
                        const int2* __restrict__ bedge,
                        const float* __restrict__ uemb, const float* __restrict__ iemb,
                        const unsigned short* __restrict__ h1, float* __restrict__ out) {
    __shared__ float lds[4 * 3 * EMB];       // [item][role][dim]
    int W    = threadIdx.x >> 6;             // wave 0..11
    int it   = W / 3;                        // item-in-block 0..3
    int w    = W % 3;                        // role: 0=user 1=pos 2=neg
    int b    = blockIdx.x * 4 + it;
    int lane = threadIdx.x & 63;
    int g = lane >> 4;
    int q = (lane & 15) * 4;
    float* ldsb = lds + it * (3 * EMB);

    int node;
    if (w == 0)      node = user[b];
    else if (w == 1) node = NUM_USERS + pos[b];
    else             node = NUM_USERS + neg[b];

    int cs  = midx[node];
    int cnt = min(bcnt[cs], BCAP);
    int s = cs * BCAP, t = s + cnt;
    float a0 = 0.f, a1 = 0.f, a2 = 0.f, a3 = 0.f;
    for (int e = s; e < t; e += 8) {
        int eA = e + g, eB = e + 4 + g;
        int2 pA = bedge[eA < t ? eA : s];
        int2 pB = bedge[eB < t ? eB : s];
        float vA = (eA < t) ? __int_as_float(pA.y) : 0.f;
        float vB = (eB < t) ? __int_as_float(pB.y) : 0.f;
        ushort4 yA = *(const ushort4*)(h1 + (size_t)pA.x * EMB + q);
        ushort4 yB = *(const ushort4*)(h1 + (size_t)pB.x * EMB + q);
        a0 = fmaf(vA, bf2f(yA.x), a0); a1 = fmaf(vA, bf2f(yA.y), a1);
        a2 = fmaf(vA, bf2f(yA.z), a2); a3 = fmaf(vA, bf2f(yA.w), a3);
        a0 = fmaf(vB, bf2f(yB.x), a0); a1 = fmaf(vB, bf2f(yB.y), a1);
        a2 = fmaf(vB, bf2f(yB.z), a2); a3 = fmaf(vB, bf2f(yB.w), a3);
    }
    a0 += __shfl_xor(a0, 16, 64); a1 += __shfl_xor(a1, 16, 64);
    a2 += __shfl_xor(a2, 16, 64); a3 += __shfl_xor(a3, 16, 64);
    a0 += __shfl_xor(a0, 32, 64); a1 += __shfl_xor(a1, 32, 64);
    a2 += __shfl_xor(a2, 32, 64); a3 += __shfl_xor(a3, 32, 64);

    if (lane < 16) {
        const float* xbp = node_ptr(node, uemb, iemb) + q;
        float4  xd = *(const float4*)xbp;
        ushort4 hn = *(const ushort4*)(h1 + (size_t)node * EMB + q);
        a0 = (a0 + xd.x + bf2f(hn.x)) / 3.0f;
        a1 = (a1 + xd.y + bf2f(hn.y)) / 3.0f;
        a2 = (a2 + xd.z + bf2f(hn.z)) / 3.0f;
        a3 = (a3 + xd.w + bf2f(hn.w)) / 3.0f;
        *(float4*)(ldsb + w * EMB + q) = make_float4(a0, a1, a2, a3);
    }
    __syncthreads();

    if (w < 2) {
        float prod = ldsb[lane] * ldsb[(w + 1) * EMB + lane];
        for (int off = 32; off; off >>= 1) prod += __shfl_xor(prod, off, 64);
        if (lane == 0) out[w * BATCH + b] = prod;
    }
}

// ---------------- launch ----------------

extern "C" void kernel_launch(void* const* d_in, const int* in_sizes, int n_in,
                              void* d_out, int out_size, void* d_ws, size_t ws_size,
                              hipStream_t stream) {
    const int*   user  = (const int*)d_in[0];
    const int*   pos   = (const int*)d_in[1];
    const int*   neg   = (const int*)d_in[2];
    const int*   erow  = (const int*)d_in[3];
    const int*   ecol  = (const int*)d_in[4];
    const float* eval_ = (const float*)d_in[5];
    const float* uemb  = (const float*)d_in[6];
    const float* iemb  = (const float*)d_in[7];
    float* out = (float*)d_out;

    char* ws = (char*)d_ws;
    // layout (bytes) — part2 sorts tmp IN-PLACE (no separate epack region):
    //   xb     : 0          .. 25,600,000   (200000*64 bf16)
    //   h1     : 25,600,000 .. 51,200,000   (bf16)
    //   tmp    : 51,200,000 .. 86,433,792   (391*11264 int2; row-sorted in place)
    //   rowext : 86,433,792 .. 88,033,792   (200000 int2)
    //   bcur   : 88,033,792 .. 88,035,360   (392 int, RELATIVE cursors)
    //   memb   : 88,035,360 .. 88,060,384   (6256 words, padded for bucket-390 mw read)
    //   need   : 88,060,384 .. 88,085,408   (6256 words, padded)
    //   bcnt   : 88,085,408 .. 88,134,560   (12288 int: bedge cursors)
    //   midx   : 88,134,560 .. 88,934,560   (200000 int: node -> canonical slot)
    //   bedge  : 88,934,560 .. 95,226,016   (12288*64 int2: batch-node edge lists)
    unsigned short* xb = (unsigned short*)(ws);
    unsigned short* h1 = (unsigned short*)(ws + 25600000);
    int2* tmp      = (int2*)(ws + 51200000);
    int2* rowext   = (int2*)(ws + 86433792);
    int*  bcur     = (int*)(ws + 88033792);
    unsigned* memb = (unsigned*)(ws + 88035360);
    unsigned* need = (unsigned*)(ws + 88060384);
    int*  bcnt     = (int*)(ws + 88085408);
    int*  midx     = (int*)(ws + 88134560);
    int2* bedge    = (int2*)(ws + 88934560);

    // zero bcur + memb + need + bcnt in one contiguous memset (100,768 B)
    hipMemsetAsync(ws + 88033792, 0, 100768, stream);

    k_part1<<<(NUM_EDGES + CHUNK - 1) / CHUNK, PTHREADS, 0, stream>>>(
        user, pos, neg, erow, ecol, eval_, uemb, iemb, xb, bcur, memb, need, midx, tmp);

    k_part2<<<NB, 1024, 0, stream>>>(bcur, tmp, rowext, memb, midx, need, bcnt, bedge);

    k_spmm1<<<(NUM_NODES * 64 + 255) / 256, 256, 0, stream>>>(rowext, tmp, xb, need, h1);

    k_final<<<BATCH / 4, 768, 0, stream>>>(user, pos, neg, midx, bcnt, bedge,
                                           uemb, iemb, h1, out);
}

// Round 10
// 295.064 us; speedup vs baseline: 1.0133x; 1.0133x over previous
//
#include <hip/hip_runtime.h>
#include <cstdint>
#include <cstddef>

#define NUM_USERS 100000
#define NUM_ITEMS 100000
#define NUM_NODES 200000
#define NUM_EDGES 4000000
#define BATCH     4096
#define EMB       64

#define NB    391          // ceil(NUM_NODES / 512) buckets (bucket = row >> 9)
#define CAP   11264        // fixed bucket capacity: mean 10240 + 10 sigma; = 11*1024
#define CHUNK 8192         // edges per block in k_part1 (489 blocks)
#define PTHREADS 1024
#define EPB   8            // CHUNK / PTHREADS
#define RPT   11           // CAP / 1024: tmp records per thread in k_part2
#define BCAP  64           // per-batch-node edge-list capacity (deg~Poisson(20))
#define NWORDS 6250        // ceil(NUM_NODES / 32) bitmap words

// ---------------- bf16 helpers (round-to-nearest-even) ----------------

__device__ __forceinline__ unsigned short f2bf(float f) {
    unsigned u = __float_as_uint(f);
    u = (u + 0x7FFFu + ((u >> 16) & 1u)) >> 16;
    return (unsigned short)u;
}
__device__ __forceinline__ float bf2f(unsigned short b) {
    return __uint_as_float(((unsigned)b) << 16);
}
// packed-bf16 unpack: int holds [lo16 = dim 2k, hi16 = dim 2k+1]
__device__ __forceinline__ float lobf(int u) { return __uint_as_float(((unsigned)u) << 16); }
__device__ __forceinline__ float hibf(int u) { return __uint_as_float(((unsigned)u) & 0xFFFF0000u); }

// ---------------- Pass 1: cvt + batch-marking + LDS-sorted partition ----------
// (byte-identical to r9-passed version)

__global__ void k_part1(const int* __restrict__ user, const int* __restrict__ pos,
                        const int* __restrict__ neg,
                        const int* __restrict__ erow, const int* __restrict__ ecol,
                        const float* __restrict__ eval_,
                        const float* __restrict__ uemb, const float* __restrict__ iemb,
                        unsigned short* __restrict__ xb,
                        int* __restrict__ bcur,
                        unsigned* __restrict__ memb, unsigned* __restrict__ need,
                        int* __restrict__ midx,
                        int2* __restrict__ tmp) {
    __shared__ int  hist[NB];
    __shared__ int  sst[512];          // inclusive scan of hist (padded)
    __shared__ int  gb[NB];            // global base per bucket
    __shared__ int  wpre[8];           // per-wave partial sums for shfl scan
    __shared__ int2 srec[CHUNK];       // 64 KB block-sorted records
    int t = threadIdx.x;
    int gid = blockIdx.x * PTHREADS + t;
    if (t < NB) hist[t] = 0;
    __syncthreads();                   // hist visible; cvt/mark/count share one region

    // fused cvt: f32 emb -> bf16 xb (3.2 grid-stride iters over 489x1024 threads)
    const int TOT8 = (NUM_NODES * EMB) / 8;              // 1.6M chunks of 8
    const size_t UELEMS = (size_t)NUM_USERS * EMB;       // divisible by 8
    for (int i = gid; i < TOT8; i += gridDim.x * PTHREADS) {
        size_t off = (size_t)i * 8;
        const float* src = (off < UELEMS) ? (uemb + off) : (iemb + (off - UELEMS));
        float4 f0 = ((const float4*)src)[0];
        float4 f1 = ((const float4*)src)[1];
        ((ushort4*)(xb + off))[0] = make_ushort4(f2bf(f0.x), f2bf(f0.y), f2bf(f0.z), f2bf(f0.w));
        ((ushort4*)(xb + off))[1] = make_ushort4(f2bf(f1.x), f2bf(f1.y), f2bf(f1.z), f2bf(f1.w));
    }
    // fused batch-node marking (consumers: k_part2, k_spmm1, k_final — later kernels)
    if (gid < 3 * BATCH) {
        int b = gid & (BATCH - 1);
        int w = gid >> 12;
        int node = (w == 0) ? user[b] : (w == 1) ? (NUM_USERS + pos[b]) : (NUM_USERS + neg[b]);
        unsigned bit = 1u << (node & 31);
        atomicOr(&memb[node >> 5], bit);
        atomicOr(&need[node >> 5], bit);   // batch nodes' own h1 rows read by k_final
        midx[node] = gid;                  // duplicate nodes: any single winner is fine
    }

    // count phase (independent of cvt/mark; no barrier between — they overlap)
    int start = blockIdx.x * CHUNK;
    int rows[EPB], ranks[EPB];
#pragma unroll
    for (int k = 0; k < EPB; ++k) {
        int e = start + t + k * PTHREADS;
        if (e < NUM_EDGES) {
            int r = erow[e];
            rows[k]  = r;
            ranks[k] = atomicAdd(&hist[r >> 9], 1);
        } else {
            rows[k] = -1;
        }
    }
    __syncthreads();

    // two-level shfl scan of hist -> inclusive sst[0..511] (3 barriers total)
    int lane = t & 63, wv8 = t >> 6;
    int v = (t < 512) ? ((t < NB) ? hist[t] : 0) : 0;
    int inc = v;
#pragma unroll
    for (int off = 1; off < 64; off <<= 1) {
        int nv = __shfl_up(inc, off, 64);
        if (lane >= off) inc += nv;
    }
    if (t < 512 && lane == 63) wpre[wv8] = inc;
    __syncthreads();
    if (t < 64) {
        int sv = (t < 8) ? wpre[t] : 0;
#pragma unroll
        for (int off = 1; off < 8; off <<= 1) {
            int nv = __shfl_up(sv, off, 64);
            if (t >= off) sv += nv;
        }
        if (t < 8) wpre[t] = sv;
    }
    __syncthreads();
    if (t < 512) sst[t] = inc + (wv8 ? wpre[wv8 - 1] : 0);
    // global cursor reservation (relative bcur)
    if (t < NB) gb[t] = atomicAdd(&bcur[t], hist[t]);
    __syncthreads();

    // LDS scatter into block-sorted order (NO side channel — r2 form)
#pragma unroll
    for (int k = 0; k < EPB; ++k) {
        if (rows[k] >= 0) {
            int e   = start + t + k * PTHREADS;
            int r   = rows[k];
            int bkt = r >> 9;
            int lp  = sst[bkt] - hist[bkt] + ranks[k];   // excl start + rank
            srec[lp] = make_int2(((r & 511) << 18) | ecol[e], __float_as_int(eval_[e]));
        }
    }
    __syncthreads();

    // coalesced copy-out: 16-lane group per bucket run (4 buckets per wave)
    int grp = t >> 4, gl = t & 15;                       // 64 groups
    for (int bkt = grp; bkt < NB; bkt += 64) {
        int c  = hist[bkt];
        int st = sst[bkt] - c;
        int g0 = gb[bkt];
        size_t base = (size_t)bkt * CAP;
        for (int j = gl; j < c; j += 16) {
            int rel = g0 + j;
            if (rel < CAP)   // overflow clamp (P ~ 1e-12, deterministic input)
                tmp[base + rel] = srec[st + j];
        }
    }
}

// ---------------- Pass 2: per-bucket row-sort IN-PLACE + batch side-channel ----
// (byte-identical to r9-passed version)

__global__ void k_part2(const int* __restrict__ bcur, int2* tmp,
                        int2* __restrict__ rowext,
                        const unsigned* __restrict__ memb, const int* __restrict__ midx,
                        unsigned* __restrict__ need,
                        int* __restrict__ bcnt, int2* __restrict__ bedge) {
    __shared__ int cnt[512];
    __shared__ int loc[512];
    __shared__ int wpre[8];
    __shared__ unsigned mw[16];
    int b = blockIdx.x, t = threadIdx.x;
    int base_row = b << 9;
    int nrows = min(512, NUM_NODES - base_row);
    int s0 = b * CAP;
    int n = min(bcur[b], CAP);
    if (t < 512) cnt[t] = 0;
    if (t < 16) mw[t] = memb[(base_row >> 5) + t];   // memb padded to 6256 words
    __syncthreads();

    int2 r[RPT];
#pragma unroll
    for (int i = 0; i < RPT; ++i) {
        int idx = t + i * 1024;
        if (idx < n) {
            r[i] = tmp[s0 + idx];
            atomicAdd(&cnt[((unsigned)r[i].x) >> 18], 1);
        }
    }
    __syncthreads();

    // two-level shfl scan of cnt -> inclusive (3 barriers)
    int lane = t & 63, wv8 = t >> 6;
    int v = (t < 512) ? cnt[t] : 0;
    int inc = v;
#pragma unroll
    for (int off = 1; off < 64; off <<= 1) {
        int nv = __shfl_up(inc, off, 64);
        if (lane >= off) inc += nv;
    }
    if (t < 512 && lane == 63) wpre[wv8] = inc;
    __syncthreads();
    if (t < 64) {
        int sv = (t < 8) ? wpre[t] : 0;
#pragma unroll
        for (int off = 1; off < 8; off <<= 1) {
            int nv = __shfl_up(sv, off, 64);
            if (t >= off) sv += nv;
        }
        if (t < 8) wpre[t] = sv;
    }
    __syncthreads();
    if (t < 512) {
        int incl = inc + (wv8 ? wpre[wv8 - 1] : 0);
        int cur = s0 + incl - v;    // exclusive, bucket-local
        if (t < nrows) rowext[base_row + t] = make_int2(cur, v);
        loc[t] = cur;
    }
    __syncthreads();

#pragma unroll
    for (int i = 0; i < RPT; ++i) {
        int idx = t + i * 1024;
        if (idx < n) {
            int2 rec = r[i];
            unsigned rl = ((unsigned)rec.x) >> 18;
            int p = atomicAdd(&loc[rl], 1);
            int col = rec.x & 0x3FFFF;
            tmp[p] = make_int2(col, rec.y);          // in-place, row bits stripped
            if ((mw[rl >> 5] >> (rl & 31)) & 1u) {   // batch-node row (~6%)
                int cs = midx[base_row + (int)rl];
                int bp = atomicAdd(&bcnt[cs], 1);
                if (bp < BCAP) bedge[cs * BCAP + bp] = make_int2(col, rec.y);
                atomicOr(&need[col >> 5], 1u << (col & 31));
            }
        }
    }
}

// ---------------- SpMM layer 1: h1 = A * x, NEEDED ROWS ONLY ----------------
// REGROUPED vs r9: 8-lane edge-groups, ushort8 (16 B) per lane -> one wave
// VMEM instruction covers 8 edges (1 KB, the coalescing sweet spot); VMEM
// wave-instruction count HALVED at identical byte traffic. This is the A/B
// for the fabric-BW-ceiling theory: if dur doesn't move and FETCH stays
// ~173 MB, spmm1 is byte-bound, not issue-bound.

__global__ void k_spmm1(const int2* __restrict__ rowext, const int2* __restrict__ epack,
                        const unsigned short* __restrict__ xb,
                        const unsigned* __restrict__ need,
                        unsigned short* __restrict__ h1) {
    int wid  = (blockIdx.x * blockDim.x + threadIdx.x) >> 6;
    int lane = threadIdx.x & 63;
    if (wid >= NUM_NODES) return;
    if (!((need[wid >> 5] >> (wid & 31)) & 1u)) return;
    int g = lane >> 3;                 // 8 edge-groups of 8 lanes
    int q = (lane & 7) * 8;            // 8 consecutive dims per lane
    int2 se = rowext[wid];
    int s = se.x, t = se.x + se.y;
    float a0 = 0.f, a1 = 0.f, a2 = 0.f, a3 = 0.f;
    float a4 = 0.f, a5 = 0.f, a6 = 0.f, a7 = 0.f;
    int e = s;
    int tfull = s + ((t - s) & ~15);
    for (; e < tfull; e += 16) {       // unpredicated hot loop, 16 edges / 4 VMEM
        int2 pA = epack[e + g];
        int2 pB = epack[e + 8 + g];
        int4 xA = *(const int4*)(xb + (size_t)pA.x * EMB + q);
        int4 xB = *(const int4*)(xb + (size_t)pB.x * EMB + q);
        float vA = __int_as_float(pA.y);
        float vB = __int_as_float(pB.y);
        a0 = fmaf(vA, lobf(xA.x), a0); a1 = fmaf(vA, hibf(xA.x), a1);
        a2 = fmaf(vA, lobf(xA.y), a2); a3 = fmaf(vA, hibf(xA.y), a3);
        a4 = fmaf(vA, lobf(xA.z), a4); a5 = fmaf(vA, hibf(xA.z), a5);
        a6 = fmaf(vA, lobf(xA.w), a6); a7 = fmaf(vA, hibf(xA.w), a7);
        a0 = fmaf(vB, lobf(xB.x), a0); a1 = fmaf(vB, hibf(xB.x), a1);
        a2 = fmaf(vB, lobf(xB.y), a2); a3 = fmaf(vB, hibf(xB.y), a3);
        a4 = fmaf(vB, lobf(xB.z), a4); a5 = fmaf(vB, hibf(xB.z), a5);
        a6 = fmaf(vB, lobf(xB.w), a6); a7 = fmaf(vB, hibf(xB.w), a7);
    }
    for (; e < t; e += 8) {            // predicated tail (<=2 iterations)
        int eA = e + g;
        int2 pA = epack[eA < t ? eA : s];
        float vA = (eA < t) ? __int_as_float(pA.y) : 0.f;
        int4 xA = *(const int4*)(xb + (size_t)pA.x * EMB + q);
        a0 = fmaf(vA, lobf(xA.x), a0); a1 = fmaf(vA, hibf(xA.x), a1);
        a2 = fmaf(vA, lobf(xA.y), a2); a3 = fmaf(vA, hibf(xA.y), a3);
        a4 = fmaf(vA, lobf(xA.z), a4); a5 = fmaf(vA, hibf(xA.z), a5);
        a6 = fmaf(vA, lobf(xA.w), a6); a7 = fmaf(vA, hibf(xA.w), a7);
    }
    // cross-group reduce (8 groups): xor 8, 16, 32
    a0 += __shfl_xor(a0, 8, 64);  a1 += __shfl_xor(a1, 8, 64);
    a2 += __shfl_xor(a2, 8, 64);  a3 += __shfl_xor(a3, 8, 64);
    a4 += __shfl_xor(a4, 8, 64);  a5 += __shfl_xor(a5, 8, 64);
    a6 += __shfl_xor(a6, 8, 64);  a7 += __shfl_xor(a7, 8, 64);
    a0 += __shfl_xor(a0, 16, 64); a1 += __shfl_xor(a1, 16, 64);
    a2 += __shfl_xor(a2, 16, 64); a3 += __shfl_xor(a3, 16, 64);
    a4 += __shfl_xor(a4, 16, 64); a5 += __shfl_xor(a5, 16, 64);
    a6 += __shfl_xor(a6, 16, 64); a7 += __shfl_xor(a7, 16, 64);
    a0 += __shfl_xor(a0, 32, 64); a1 += __shfl_xor(a1, 32, 64);
    a2 += __shfl_xor(a2, 32, 64); a3 += __shfl_xor(a3, 32, 64);
    a4 += __shfl_xor(a4, 32, 64); a5 += __shfl_xor(a5, 32, 64);
    a6 += __shfl_xor(a6, 32, 64); a7 += __shfl_xor(a7, 32, 64);
    if (lane < 8) {
        ushort us[8];
        us[0] = f2bf(a0); us[1] = f2bf(a1); us[2] = f2bf(a2); us[3] = f2bf(a3);
        us[4] = f2bf(a4); us[5] = f2bf(a5); us[6] = f2bf(a6); us[7] = f2bf(a7);
        int4* dst = (int4*)(h1 + (size_t)wid * EMB + q);
        *dst = *(const int4*)us;
    }
}

// ---------------- Fused layer 2 + scoring: 4 batch items per block ----------
// (byte-identical to r9-passed version)

__device__ __forceinline__ const float* node_ptr(int c, const float* __restrict__ uemb,
                                                 const float* __restrict__ iemb) {
    return (c < NUM_USERS) ? (uemb + (size_t)c * EMB)
                           : (iemb + (size_t)(c - NUM_USERS) * EMB);
}

__global__ void k_final(const int* __restrict__ user, const int* __restrict__ pos,
                        const int* __restrict__ neg,
                        const int* __restrict__ midx, const int* __restrict__ bcnt,
                        const int2* __restrict__ bedge,
                        const float* __restrict__ uemb, const float* __restrict__ iemb,
                        const unsigned short* __restrict__ h1, float* __restrict__ out) {
    __shared__ float lds[4 * 3 * EMB];       // [item][role][dim]
    int W    = threadIdx.x >> 6;             // wave 0..11
    int it   = W / 3;                        // item-in-block 0..3
    int w    = W % 3;                        // role: 0=user 1=pos 2=neg
    int b    = blockIdx.x * 4 + it;
    int lane = threadIdx.x & 63;
    int g = lane >> 4;
    int q = (lane & 15) * 4;
    float* ldsb = lds + it * (3 * EMB);

    int node;
    if (w == 0)      node = user[b];
    else if (w == 1) node = NUM_USERS + pos[b];
    else             node = NUM_USERS + neg[b];

    int cs  = midx[node];
    int cnt = min(bcnt[cs], BCAP);
    int s = cs * BCAP, t = s + cnt;
    float a0 = 0.f, a1 = 0.f, a2 = 0.f, a3 = 0.f;
    for (int e = s; e < t; e += 8) {
        int eA = e + g, eB = e + 4 + g;
        int2 pA = bedge[eA < t ? eA : s];
        int2 pB = bedge[eB < t ? eB : s];
        float vA = (eA < t) ? __int_as_float(pA.y) : 0.f;
        float vB = (eB < t) ? __int_as_float(pB.y) : 0.f;
        ushort4 yA = *(const ushort4*)(h1 + (size_t)pA.x * EMB + q);
        ushort4 yB = *(const ushort4*)(h1 + (size_t)pB.x * EMB + q);
        a0 = fmaf(vA, bf2f(yA.x), a0); a1 = fmaf(vA, bf2f(yA.y), a1);
        a2 = fmaf(vA, bf2f(yA.z), a2); a3 = fmaf(vA, bf2f(yA.w), a3);
        a0 = fmaf(vB, bf2f(yB.x), a0); a1 = fmaf(vB, bf2f(yB.y), a1);
        a2 = fmaf(vB, bf2f(yB.z), a2); a3 = fmaf(vB, bf2f(yB.w), a3);
    }
    a0 += __shfl_xor(a0, 16, 64); a1 += __shfl_xor(a1, 16, 64);
    a2 += __shfl_xor(a2, 16, 64); a3 += __shfl_xor(a3, 16, 64);
    a0 += __shfl_xor(a0, 32, 64); a1 += __shfl_xor(a1, 32, 64);
    a2 += __shfl_xor(a2, 32, 64); a3 += __shfl_xor(a3, 32, 64);

    if (lane < 16) {
        const float* xbp = node_ptr(node, uemb, iemb) + q;
        float4  xd = *(const float4*)xbp;
        ushort4 hn = *(const ushort4*)(h1 + (size_t)node * EMB + q);
        a0 = (a0 + xd.x + bf2f(hn.x)) / 3.0f;
        a1 = (a1 + xd.y + bf2f(hn.y)) / 3.0f;
        a2 = (a2 + xd.z + bf2f(hn.z)) / 3.0f;
        a3 = (a3 + xd.w + bf2f(hn.w)) / 3.0f;
        *(float4*)(ldsb + w * EMB + q) = make_float4(a0, a1, a2, a3);
    }
    __syncthreads();

    if (w < 2) {
        float prod = ldsb[lane] * ldsb[(w + 1) * EMB + lane];
        for (int off = 32; off; off >>= 1) prod += __shfl_xor(prod, off, 64);
        if (lane == 0) out[w * BATCH + b] = prod;
    }
}

// ---------------- launch ----------------

extern "C" void kernel_launch(void* const* d_in, const int* in_sizes, int n_in,
                              void* d_out, int out_size, void* d_ws, size_t ws_size,
                              hipStream_t stream) {
    const int*   user  = (const int*)d_in[0];
    const int*   pos   = (const int*)d_in[1];
    const int*   neg   = (const int*)d_in[2];
    const int*   erow  = (const int*)d_in[3];
    const int*   ecol  = (const int*)d_in[4];
    const float* eval_ = (const float*)d_in[5];
    const float* uemb  = (const float*)d_in[6];
    const float* iemb  = (const float*)d_in[7];
    float* out = (float*)d_out;

    char* ws = (char*)d_ws;
    // layout (bytes) — part2 sorts tmp IN-PLACE (no separate epack region):
    //   xb     : 0          .. 25,600,000   (200000*64 bf16)
    //   h1     : 25,600,000 .. 51,200,000   (bf16)
    //   tmp    : 51,200,000 .. 86,433,792   (391*11264 int2; row-sorted in place)
    //   rowext : 86,433,792 .. 88,033,792   (200000 int2)
    //   bcur   : 88,033,792 .. 88,035,360   (392 int, RELATIVE cursors)
    //   memb   : 88,035,360 .. 88,060,384   (6256 words, padded for bucket-390 mw read)
    //   need   : 88,060,384 .. 88,085,408   (6256 words, padded)
    //   bcnt   : 88,085,408 .. 88,134,560   (12288 int: bedge cursors)
    //   midx   : 88,134,560 .. 88,934,560   (200000 int: node -> canonical slot)
    //   bedge  : 88,934,560 .. 95,226,016   (12288*64 int2: batch-node edge lists)
    unsigned short* xb = (unsigned short*)(ws);
    unsigned short* h1 = (unsigned short*)(ws + 25600000);
    int2* tmp      = (int2*)(ws + 51200000);
    int2* rowext   = (int2*)(ws + 86433792);
    int*  bcur     = (int*)(ws + 88033792);
    unsigned* memb = (unsigned*)(ws + 88035360);
    unsigned* need = (unsigned*)(ws + 88060384);
    int*  bcnt     = (int*)(ws + 88085408);
    int*  midx     = (int*)(ws + 88134560);
    int2* bedge    = (int2*)(ws + 88934560);

    // zero bcur + memb + need + bcnt in one contiguous memset (100,768 B)
    hipMemsetAsync(ws + 88033792, 0, 100768, stream);

    k_part1<<<(NUM_EDGES + CHUNK - 1) / CHUNK, PTHREADS, 0, stream>>>(
        user, pos, neg, erow, ecol, eval_, uemb, iemb, xb, bcur, memb, need, midx, tmp);

    k_part2<<<NB, 1024, 0, stream>>>(bcur, tmp, rowext, memb, midx, need, bcnt, bedge);

    k_spmm1<<<(NUM_NODES * 64 + 255) / 256, 256, 0, stream>>>(rowext, tmp, xb, need, h1);

    k_final<<<BATCH / 4, 768, 0, stream>>>(user, pos, neg, midx, bcnt, bedge,
                                           uemb, iemb, h1, out);
}